// Round 1
// baseline (920.157 us; speedup 1.0000x reference)
//
#include <hip/hip_runtime.h>
#include <math.h>

// ---------------------------------------------------------------------------
// GAT 2-layer pipeline for MI355X.
// N=50000 nodes, E=850000 edges (incl self loops), feat 256, H=4 x 64 -> 256.
//
// Pipeline (all on `stream`):
//   CSR build (zero, histogram, scan, scatter)  -- graph identical both layers
//   GEMM1: hp = x @ W1^T                         (fp32 tiled, 64x64x64)
//   s1:    per-node per-head attention scalars
//   AGG1:  per-dst online softmax + aggregate + relu -> h (stored in d_out)
//   GEMM2: hp = h @ W2^T
//   s2
//   AGG2:  -> d_out
// ---------------------------------------------------------------------------

// C[M x 256] = A[M x 256] * B[256 x 256]^T   (A, B row-major)
__global__ __launch_bounds__(256) void gemm_abt(const float* __restrict__ A,
                                                const float* __restrict__ B,
                                                float* __restrict__ C, int M) {
    // LDS tiles stored transposed: As[k][m], padded row stride 68 (16B aligned,
    // breaks the stride-64 bank pattern).
    __shared__ float As[64][68];
    __shared__ float Bs[64][68];
    const int tid = threadIdx.x;
    const int m0 = blockIdx.x * 64;
    const int n0 = blockIdx.y * 64;
    const int tx = tid % 16, ty = tid / 16;   // 4x4 micro-tile per thread
    const int c4 = tid % 16, r0 = tid / 16;   // staging map

    float acc[4][4] = {};
    for (int k0 = 0; k0 < 256; k0 += 64) {
        #pragma unroll
        for (int p = 0; p < 4; ++p) {
            int r = r0 + p * 16;
            int gm = m0 + r;
            float4 va = (gm < M) ? *(const float4*)&A[(size_t)gm * 256 + k0 + c4 * 4]
                                 : make_float4(0.f, 0.f, 0.f, 0.f);
            As[c4 * 4 + 0][r] = va.x; As[c4 * 4 + 1][r] = va.y;
            As[c4 * 4 + 2][r] = va.z; As[c4 * 4 + 3][r] = va.w;
            float4 vb = *(const float4*)&B[(size_t)(n0 + r) * 256 + k0 + c4 * 4];
            Bs[c4 * 4 + 0][r] = vb.x; Bs[c4 * 4 + 1][r] = vb.y;
            Bs[c4 * 4 + 2][r] = vb.z; Bs[c4 * 4 + 3][r] = vb.w;
        }
        __syncthreads();
        #pragma unroll 8
        for (int k = 0; k < 64; ++k) {
            float4 av = *(const float4*)&As[k][ty * 4];
            float4 bv = *(const float4*)&Bs[k][tx * 4];
            float a[4] = {av.x, av.y, av.z, av.w};
            float b[4] = {bv.x, bv.y, bv.z, bv.w};
            #pragma unroll
            for (int i = 0; i < 4; ++i)
                #pragma unroll
                for (int j = 0; j < 4; ++j)
                    acc[i][j] = fmaf(a[i], b[j], acc[i][j]);
        }
        __syncthreads();
    }
    #pragma unroll
    for (int i = 0; i < 4; ++i) {
        int gm = m0 + ty * 4 + i;
        if (gm < M) {
            float4 v = make_float4(acc[i][0], acc[i][1], acc[i][2], acc[i][3]);
            *(float4*)&C[(size_t)gm * 256 + n0 + tx * 4] = v;
        }
    }
}

// -------------------- CSR build --------------------
__global__ void zero_int(int* __restrict__ p, int n) {
    int i = blockIdx.x * 256 + threadIdx.x;
    if (i < n) p[i] = 0;
}

__global__ void hist_kernel(const int* __restrict__ dst, int* __restrict__ deg, int E) {
    int i = blockIdx.x * 256 + threadIdx.x;
    if (i < E) atomicAdd(&deg[dst[i]], 1);
}

// single-block exclusive scan over n entries; writes offs[0..n] and cur[0..n-1]
__global__ __launch_bounds__(1024) void scan_kernel(const int* __restrict__ deg,
                                                    int* __restrict__ offs,
                                                    int* __restrict__ cur, int n) {
    __shared__ int sh[1024];
    __shared__ int carry_sh;
    int tid = threadIdx.x;
    if (tid == 0) carry_sh = 0;
    __syncthreads();
    for (int base = 0; base < n; base += 1024) {
        int i = base + tid;
        int v = (i < n) ? deg[i] : 0;
        sh[tid] = v;
        __syncthreads();
        #pragma unroll
        for (int off = 1; off < 1024; off <<= 1) {
            int t2 = (tid >= off) ? sh[tid - off] : 0;
            __syncthreads();
            sh[tid] += t2;
            __syncthreads();
        }
        int inc = sh[tid];
        int carry = carry_sh;
        if (i < n) {
            int ex = carry + inc - v;
            offs[i] = ex;
            cur[i] = ex;
        }
        __syncthreads();
        if (tid == 1023) carry_sh = carry + inc;
        __syncthreads();
    }
    if (tid == 0) offs[n] = carry_sh;
}

__global__ void scatter_kernel(const int* __restrict__ src, const int* __restrict__ dst,
                               int* __restrict__ cur, int* __restrict__ sorted, int E) {
    int i = blockIdx.x * 256 + threadIdx.x;
    if (i < E) {
        int p = atomicAdd(&cur[dst[i]], 1);
        sorted[p] = src[i];
    }
}

// -------------------- attention scalars --------------------
// s_src[n,h] = sum_f hp[n, h*NF+f] * a_src[h*NF+f]  (a arrays are 256 flat)
template <int NH>
__global__ __launch_bounds__(256) void scompute(const float* __restrict__ hp,
                                                const float* __restrict__ a_src,
                                                const float* __restrict__ a_dst,
                                                float* __restrict__ s_src,
                                                float* __restrict__ s_dst) {
    __shared__ float w1[4], w2[4];
    int node = blockIdx.x;
    int t = threadIdx.x;
    float v = hp[(size_t)node * 256 + t];
    float p1 = v * a_src[t];
    float p2 = v * a_dst[t];
    #pragma unroll
    for (int off = 32; off > 0; off >>= 1) {
        p1 += __shfl_down(p1, off, 64);
        p2 += __shfl_down(p2, off, 64);
    }
    int wave = t >> 6, lane = t & 63;
    if constexpr (NH == 4) {
        if (lane == 0) {
            s_src[node * 4 + wave] = p1;
            s_dst[node * 4 + wave] = p2;
        }
    } else {
        if (lane == 0) { w1[wave] = p1; w2[wave] = p2; }
        __syncthreads();
        if (t == 0) {
            s_src[node] = w1[0] + w1[1] + w1[2] + w1[3];
            s_dst[node] = w2[0] + w2[1] + w2[2] + w2[3];
        }
    }
}

// -------------------- per-dst online-softmax aggregation --------------------
// block = 256 threads = NH*NF; thread t -> (head = t/NF, feat = t%NF)
template <int NH, int NF, bool RELU>
__global__ __launch_bounds__(256) void aggregate(const float* __restrict__ hp,
                                                 const float* __restrict__ ssrc,
                                                 const float* __restrict__ sdst,
                                                 const int* __restrict__ offs,
                                                 const int* __restrict__ sorted,
                                                 float* __restrict__ out) {
    int node = blockIdx.x;
    int t = threadIdx.x;
    int head = t / NF;
    float sd = sdst[node * NH + head];
    int b = offs[node], e = offs[node + 1];
    float m = -INFINITY, l = 0.f, acc = 0.f;
    for (int i = b; i < e; ++i) {
        int s = sorted[i];
        float ev = ssrc[s * NH + head] + sd;
        ev = ev > 0.f ? ev : 0.2f * ev;
        float m2 = fmaxf(m, ev);
        float sc = __expf(m - m2);   // exp(-inf)=0 on first edge
        float p = __expf(ev - m2);
        l = l * sc + p;
        acc = acc * sc + p * hp[(size_t)s * 256 + t];
        m = m2;
    }
    float o = acc / (l + 1e-16f);
    if (RELU) o = fmaxf(o, 0.f);
    out[(size_t)node * 256 + t] = o;
}

// ---------------------------------------------------------------------------
extern "C" void kernel_launch(void* const* d_in, const int* in_sizes, int n_in,
                              void* d_out, int out_size, void* d_ws, size_t ws_size,
                              hipStream_t stream) {
    const float* x   = (const float*)d_in[0];
    const int*   ei  = (const int*)d_in[1];
    const float* W1  = (const float*)d_in[2];
    const float* a1s = (const float*)d_in[3];
    const float* a1d = (const float*)d_in[4];
    const float* W2  = (const float*)d_in[5];
    const float* a2s = (const float*)d_in[6];
    const float* a2d = (const float*)d_in[7];
    float* out = (float*)d_out;

    const int N = in_sizes[0] / 256;
    const int E = in_sizes[1] / 2;
    const int* src = ei;
    const int* dst = ei + E;

    // workspace carve-up
    float* hp   = (float*)d_ws;                 // N*256
    float* ssrc = hp + (size_t)N * 256;         // N*4
    float* sdst = ssrc + (size_t)N * 4;         // N*4
    int*   deg  = (int*)(sdst + (size_t)N * 4); // N
    int*   offs = deg + N;                      // N+1
    int*   cur  = offs + N + 1;                 // N
    int*   sorted = cur + N;                    // E

    // ---- CSR build (same graph reused by both layers) ----
    zero_int<<<(N + 255) / 256, 256, 0, stream>>>(deg, N);
    hist_kernel<<<(E + 255) / 256, 256, 0, stream>>>(dst, deg, E);
    scan_kernel<<<1, 1024, 0, stream>>>(deg, offs, cur, N);
    scatter_kernel<<<(E + 255) / 256, 256, 0, stream>>>(src, dst, cur, sorted, E);

    dim3 gg((N + 63) / 64, 4);

    // ---- layer 1 ----
    gemm_abt<<<gg, 256, 0, stream>>>(x, W1, hp, N);
    scompute<4><<<N, 256, 0, stream>>>(hp, a1s, a1d, ssrc, sdst);
    aggregate<4, 64, true><<<N, 256, 0, stream>>>(hp, ssrc, sdst, offs, sorted, out);

    // ---- layer 2 (h lives in d_out; dead before final aggregate overwrites) ----
    gemm_abt<<<gg, 256, 0, stream>>>(out, W2, hp, N);
    scompute<1><<<N, 256, 0, stream>>>(hp, a2s, a2d, ssrc, sdst);
    aggregate<1, 256, false><<<N, 256, 0, stream>>>(hp, ssrc, sdst, offs, sorted, out);
}

// Round 2
// 846.796 us; speedup vs baseline: 1.0866x; 1.0866x over previous
//
#include <hip/hip_runtime.h>
#include <math.h>

// ---------------------------------------------------------------------------
// GAT 2-layer pipeline for MI355X.
// N=50000 nodes, E=850000 edges (incl self loops), feat 256, H=4 x 64 -> 256.
//
// Pipeline (all on `stream`):
//   CSR build (zero, histogram, scan, scatter)  -- graph identical both layers
//   GEMM1: hp = x @ W1^T                         (fp32 tiled, 64x64x64)
//   s1:    per-node per-head attention scalars
//   STATS1: per-(dst,head) softmax max + 1/sum   (removes serial chain from agg)
//   AGG1:  per-dst aggregate + relu -> h (stored in d_out)
//   GEMM2: hp = h @ W2^T
//   s2, STATS2, AGG2 -> d_out
// ---------------------------------------------------------------------------

// C[M x 256] = A[M x 256] * B[256 x 256]^T   (A, B row-major)
__global__ __launch_bounds__(256) void gemm_abt(const float* __restrict__ A,
                                                const float* __restrict__ B,
                                                float* __restrict__ C, int M) {
    __shared__ float As[64][68];
    __shared__ float Bs[64][68];
    const int tid = threadIdx.x;
    const int m0 = blockIdx.x * 64;
    const int n0 = blockIdx.y * 64;
    const int tx = tid % 16, ty = tid / 16;   // 4x4 micro-tile per thread
    const int c4 = tid % 16, r0 = tid / 16;   // staging map

    float acc[4][4] = {};
    for (int k0 = 0; k0 < 256; k0 += 64) {
        #pragma unroll
        for (int p = 0; p < 4; ++p) {
            int r = r0 + p * 16;
            int gm = m0 + r;
            float4 va = (gm < M) ? *(const float4*)&A[(size_t)gm * 256 + k0 + c4 * 4]
                                 : make_float4(0.f, 0.f, 0.f, 0.f);
            As[c4 * 4 + 0][r] = va.x; As[c4 * 4 + 1][r] = va.y;
            As[c4 * 4 + 2][r] = va.z; As[c4 * 4 + 3][r] = va.w;
            float4 vb = *(const float4*)&B[(size_t)(n0 + r) * 256 + k0 + c4 * 4];
            Bs[c4 * 4 + 0][r] = vb.x; Bs[c4 * 4 + 1][r] = vb.y;
            Bs[c4 * 4 + 2][r] = vb.z; Bs[c4 * 4 + 3][r] = vb.w;
        }
        __syncthreads();
        #pragma unroll 8
        for (int k = 0; k < 64; ++k) {
            float4 av = *(const float4*)&As[k][ty * 4];
            float4 bv = *(const float4*)&Bs[k][tx * 4];
            float a[4] = {av.x, av.y, av.z, av.w};
            float b[4] = {bv.x, bv.y, bv.z, bv.w};
            #pragma unroll
            for (int i = 0; i < 4; ++i)
                #pragma unroll
                for (int j = 0; j < 4; ++j)
                    acc[i][j] = fmaf(a[i], b[j], acc[i][j]);
        }
        __syncthreads();
    }
    #pragma unroll
    for (int i = 0; i < 4; ++i) {
        int gm = m0 + ty * 4 + i;
        if (gm < M) {
            float4 v = make_float4(acc[i][0], acc[i][1], acc[i][2], acc[i][3]);
            *(float4*)&C[(size_t)gm * 256 + n0 + tx * 4] = v;
        }
    }
}

// -------------------- CSR build --------------------
__global__ void zero_int(int* __restrict__ p, int n) {
    int i = blockIdx.x * 256 + threadIdx.x;
    if (i < n) p[i] = 0;
}

__global__ void hist_kernel(const int* __restrict__ dst, int* __restrict__ deg, int E) {
    int i = blockIdx.x * 256 + threadIdx.x;
    if (i < E) atomicAdd(&deg[dst[i]], 1);
}

// single-block exclusive scan over n entries; writes offs[0..n] and cur[0..n-1]
__global__ __launch_bounds__(1024) void scan_kernel(const int* __restrict__ deg,
                                                    int* __restrict__ offs,
                                                    int* __restrict__ cur, int n) {
    __shared__ int sh[1024];
    __shared__ int carry_sh;
    int tid = threadIdx.x;
    if (tid == 0) carry_sh = 0;
    __syncthreads();
    for (int base = 0; base < n; base += 1024) {
        int i = base + tid;
        int v = (i < n) ? deg[i] : 0;
        sh[tid] = v;
        __syncthreads();
        #pragma unroll
        for (int off = 1; off < 1024; off <<= 1) {
            int t2 = (tid >= off) ? sh[tid - off] : 0;
            __syncthreads();
            sh[tid] += t2;
            __syncthreads();
        }
        int inc = sh[tid];
        int carry = carry_sh;
        if (i < n) {
            int ex = carry + inc - v;
            offs[i] = ex;
            cur[i] = ex;
        }
        __syncthreads();
        if (tid == 1023) carry_sh = carry + inc;
        __syncthreads();
    }
    if (tid == 0) offs[n] = carry_sh;
}

__global__ void scatter_kernel(const int* __restrict__ src, const int* __restrict__ dst,
                               int* __restrict__ cur, int* __restrict__ sorted, int E) {
    int i = blockIdx.x * 256 + threadIdx.x;
    if (i < E) {
        int p = atomicAdd(&cur[dst[i]], 1);
        sorted[p] = src[i];
    }
}

// -------------------- attention scalars --------------------
template <int NH>
__global__ __launch_bounds__(256) void scompute(const float* __restrict__ hp,
                                                const float* __restrict__ a_src,
                                                const float* __restrict__ a_dst,
                                                float* __restrict__ s_src,
                                                float* __restrict__ s_dst) {
    __shared__ float w1[4], w2[4];
    int node = blockIdx.x;
    int t = threadIdx.x;
    float v = hp[(size_t)node * 256 + t];
    float p1 = v * a_src[t];
    float p2 = v * a_dst[t];
    #pragma unroll
    for (int off = 32; off > 0; off >>= 1) {
        p1 += __shfl_down(p1, off, 64);
        p2 += __shfl_down(p2, off, 64);
    }
    int wave = t >> 6, lane = t & 63;
    if constexpr (NH == 4) {
        if (lane == 0) {
            s_src[node * 4 + wave] = p1;
            s_dst[node * 4 + wave] = p2;
        }
    } else {
        if (lane == 0) { w1[wave] = p1; w2[wave] = p2; }
        __syncthreads();
        if (t == 0) {
            s_src[node] = w1[0] + w1[1] + w1[2] + w1[3];
            s_dst[node] = w2[0] + w2[1] + w2[2] + w2[3];
        }
    }
}

// -------------------- softmax stats: per-(dst,head) max and 1/sum ----------
template <int NH>
__global__ __launch_bounds__(256) void softmax_stats(const float* __restrict__ ssrc,
                                                     const float* __restrict__ sdst,
                                                     const int* __restrict__ offs,
                                                     const int* __restrict__ sorted,
                                                     float* __restrict__ m_out,
                                                     float* __restrict__ linv_out,
                                                     int N) {
    int t = blockIdx.x * 256 + threadIdx.x;
    int node = t / NH, h = t % NH;
    if (node >= N) return;
    float sd = sdst[node * NH + h];
    int b = offs[node], e = offs[node + 1];
    float m = -INFINITY;
    for (int i = b; i < e; ++i) {
        float ev = ssrc[sorted[i] * NH + h] + sd;
        ev = ev > 0.f ? ev : 0.2f * ev;
        m = fmaxf(m, ev);
    }
    float l = 0.f;
    for (int i = b; i < e; ++i) {
        float ev = ssrc[sorted[i] * NH + h] + sd;
        ev = ev > 0.f ? ev : 0.2f * ev;
        l += __expf(ev - m);
    }
    m_out[node * NH + h] = m;
    linv_out[node * NH + h] = 1.0f / (l + 1e-16f);
}

// -------------------- per-dst aggregation (no serial chain) ----------------
// block = 256 threads = NH*NF; thread t -> (head = t/NF, feat = t%NF)
template <int NH, int NF, bool RELU>
__global__ __launch_bounds__(256) void aggregate2(const float* __restrict__ hp,
                                                  const float* __restrict__ ssrc,
                                                  const float* __restrict__ sdst,
                                                  const float* __restrict__ m_arr,
                                                  const float* __restrict__ linv_arr,
                                                  const int* __restrict__ offs,
                                                  const int* __restrict__ sorted,
                                                  float* __restrict__ out) {
    int node = blockIdx.x;
    int t = threadIdx.x;
    int head = t / NF;
    float sd = sdst[node * NH + head];
    float m = m_arr[node * NH + head];
    float linv = linv_arr[node * NH + head];
    int b = offs[node], e = offs[node + 1];
    float acc = 0.f;
    #pragma unroll 2
    for (int i = b; i < e; ++i) {
        int s = sorted[i];
        float ev = ssrc[s * NH + head] + sd;
        ev = ev > 0.f ? ev : 0.2f * ev;
        float p = __expf(ev - m);
        acc = fmaf(p, hp[(size_t)s * 256 + t], acc);
    }
    float o = acc * linv;
    if (RELU) o = fmaxf(o, 0.f);
    out[(size_t)node * 256 + t] = o;
}

// ---------------------------------------------------------------------------
extern "C" void kernel_launch(void* const* d_in, const int* in_sizes, int n_in,
                              void* d_out, int out_size, void* d_ws, size_t ws_size,
                              hipStream_t stream) {
    const float* x   = (const float*)d_in[0];
    const int*   ei  = (const int*)d_in[1];
    const float* W1  = (const float*)d_in[2];
    const float* a1s = (const float*)d_in[3];
    const float* a1d = (const float*)d_in[4];
    const float* W2  = (const float*)d_in[5];
    const float* a2s = (const float*)d_in[6];
    const float* a2d = (const float*)d_in[7];
    float* out = (float*)d_out;

    const int N = in_sizes[0] / 256;
    const int E = in_sizes[1] / 2;
    const int* src = ei;
    const int* dst = ei + E;

    // workspace carve-up (m aliases deg, linv aliases cur — CSR-build temps
    // are dead before softmax_stats writes m/linv)
    float* hp   = (float*)d_ws;                    // N*256
    float* ssrc = hp + (size_t)N * 256;            // N*4
    float* sdst = ssrc + (size_t)N * 4;            // N*4
    float* marr = sdst + (size_t)N * 4;            // N*4  (aliases deg)
    float* linv = marr + (size_t)N * 4;            // N*4  (aliases cur)
    int*   deg  = (int*)marr;
    int*   cur  = (int*)linv;
    int*   offs = (int*)(linv + (size_t)N * 4);    // N+1
    int*   sorted = offs + N + 1;                  // E

    // ---- CSR build (same graph reused by both layers) ----
    zero_int<<<(N + 255) / 256, 256, 0, stream>>>(deg, N);
    hist_kernel<<<(E + 255) / 256, 256, 0, stream>>>(dst, deg, E);
    scan_kernel<<<1, 1024, 0, stream>>>(deg, offs, cur, N);
    scatter_kernel<<<(E + 255) / 256, 256, 0, stream>>>(src, dst, cur, sorted, E);

    dim3 gg((N + 63) / 64, 4);

    // ---- layer 1 ----
    gemm_abt<<<gg, 256, 0, stream>>>(x, W1, hp, N);
    scompute<4><<<N, 256, 0, stream>>>(hp, a1s, a1d, ssrc, sdst);
    softmax_stats<4><<<(N * 4 + 255) / 256, 256, 0, stream>>>(ssrc, sdst, offs, sorted, marr, linv, N);
    aggregate2<4, 64, true><<<N, 256, 0, stream>>>(hp, ssrc, sdst, marr, linv, offs, sorted, out);

    // ---- layer 2 (h lives in d_out; dead before final aggregate overwrites) ----
    gemm_abt<<<gg, 256, 0, stream>>>(out, W2, hp, N);
    scompute<1><<<N, 256, 0, stream>>>(hp, a2s, a2d, ssrc, sdst);
    softmax_stats<1><<<(N + 255) / 256, 256, 0, stream>>>(ssrc, sdst, offs, sorted, marr, linv, N);
    aggregate2<1, 256, false><<<N, 256, 0, stream>>>(hp, ssrc, sdst, marr, linv, offs, sorted, out);
}

// Round 3
// 737.206 us; speedup vs baseline: 1.2482x; 1.1487x over previous
//
#include <hip/hip_runtime.h>
#include <math.h>

// ---------------------------------------------------------------------------
// GAT 2-layer pipeline for MI355X.
// N=50000 nodes, E=850000 edges (incl self loops), feat 256, H=4 x 64 -> 256.
//
//   CSR build: zero, hist, two-level scan (scan1/scan2/scan3), scatter
//   GEMM:  hp = A @ W^T  (fp32 tiled 64x64)
//   scompute: per-node per-head attention scalars
//   softmax_stats: per-(dst,head) max + 1/sum, AND writes p=exp(ev-m) per edge
//   aggregate3: wave-per-node, float4-per-lane gather+fma only
// ---------------------------------------------------------------------------

__global__ __launch_bounds__(256) void gemm_abt(const float* __restrict__ A,
                                                const float* __restrict__ B,
                                                float* __restrict__ C, int M) {
    __shared__ float As[64][68];
    __shared__ float Bs[64][68];
    const int tid = threadIdx.x;
    const int m0 = blockIdx.x * 64;
    const int n0 = blockIdx.y * 64;
    const int tx = tid % 16, ty = tid / 16;
    const int c4 = tid % 16, r0 = tid / 16;

    float acc[4][4] = {};
    for (int k0 = 0; k0 < 256; k0 += 64) {
        #pragma unroll
        for (int p = 0; p < 4; ++p) {
            int r = r0 + p * 16;
            int gm = m0 + r;
            float4 va = (gm < M) ? *(const float4*)&A[(size_t)gm * 256 + k0 + c4 * 4]
                                 : make_float4(0.f, 0.f, 0.f, 0.f);
            As[c4 * 4 + 0][r] = va.x; As[c4 * 4 + 1][r] = va.y;
            As[c4 * 4 + 2][r] = va.z; As[c4 * 4 + 3][r] = va.w;
            float4 vb = *(const float4*)&B[(size_t)(n0 + r) * 256 + k0 + c4 * 4];
            Bs[c4 * 4 + 0][r] = vb.x; Bs[c4 * 4 + 1][r] = vb.y;
            Bs[c4 * 4 + 2][r] = vb.z; Bs[c4 * 4 + 3][r] = vb.w;
        }
        __syncthreads();
        #pragma unroll 8
        for (int k = 0; k < 64; ++k) {
            float4 av = *(const float4*)&As[k][ty * 4];
            float4 bv = *(const float4*)&Bs[k][tx * 4];
            float a[4] = {av.x, av.y, av.z, av.w};
            float b[4] = {bv.x, bv.y, bv.z, bv.w};
            #pragma unroll
            for (int i = 0; i < 4; ++i)
                #pragma unroll
                for (int j = 0; j < 4; ++j)
                    acc[i][j] = fmaf(a[i], b[j], acc[i][j]);
        }
        __syncthreads();
    }
    #pragma unroll
    for (int i = 0; i < 4; ++i) {
        int gm = m0 + ty * 4 + i;
        if (gm < M) {
            float4 v = make_float4(acc[i][0], acc[i][1], acc[i][2], acc[i][3]);
            *(float4*)&C[(size_t)gm * 256 + n0 + tx * 4] = v;
        }
    }
}

// -------------------- CSR build --------------------
__global__ void zero_int(int* __restrict__ p, int n) {
    int i = blockIdx.x * 256 + threadIdx.x;
    if (i < n) p[i] = 0;
}

__global__ void hist_kernel(const int* __restrict__ dst, int* __restrict__ deg, int E) {
    int i = blockIdx.x * 256 + threadIdx.x;
    if (i < E) atomicAdd(&deg[dst[i]], 1);
}

// two-level scan: scan1 (per-block local exclusive + block sums),
// scan2 (scan the block sums, write grand total), scan3 (add base)
__global__ __launch_bounds__(1024) void scan1(const int* __restrict__ deg,
                                              int* __restrict__ lex,
                                              int* __restrict__ bsums, int n) {
    __shared__ int sh[1024];
    int tid = threadIdx.x;
    int i = blockIdx.x * 1024 + tid;
    int v = (i < n) ? deg[i] : 0;
    sh[tid] = v;
    __syncthreads();
    #pragma unroll
    for (int off = 1; off < 1024; off <<= 1) {
        int t2 = (tid >= off) ? sh[tid - off] : 0;
        __syncthreads();
        sh[tid] += t2;
        __syncthreads();
    }
    if (i < n) lex[i] = sh[tid] - v;
    if (tid == 1023) bsums[blockIdx.x] = sh[1023];
}

__global__ __launch_bounds__(1024) void scan2(const int* __restrict__ bsums,
                                              int* __restrict__ boffs,
                                              int* __restrict__ offs, int nb, int n) {
    __shared__ int sh[1024];
    int tid = threadIdx.x;
    int v = (tid < nb) ? bsums[tid] : 0;
    sh[tid] = v;
    __syncthreads();
    #pragma unroll
    for (int off = 1; off < 1024; off <<= 1) {
        int t2 = (tid >= off) ? sh[tid - off] : 0;
        __syncthreads();
        sh[tid] += t2;
        __syncthreads();
    }
    if (tid < nb) boffs[tid] = sh[tid] - v;
    if (tid == nb - 1) offs[n] = sh[tid];
}

__global__ __launch_bounds__(1024) void scan3(int* __restrict__ offs,
                                              int* __restrict__ cur,
                                              const int* __restrict__ boffs, int n) {
    int i = blockIdx.x * 1024 + threadIdx.x;
    if (i < n) {
        int o = offs[i] + boffs[blockIdx.x];
        offs[i] = o;
        cur[i] = o;
    }
}

__global__ void scatter_kernel(const int* __restrict__ src, const int* __restrict__ dst,
                               int* __restrict__ cur, int* __restrict__ sorted, int E) {
    int i = blockIdx.x * 256 + threadIdx.x;
    if (i < E) {
        int p = atomicAdd(&cur[dst[i]], 1);
        sorted[p] = src[i];
    }
}

// -------------------- attention scalars --------------------
template <int NH>
__global__ __launch_bounds__(256) void scompute(const float* __restrict__ hp,
                                                const float* __restrict__ a_src,
                                                const float* __restrict__ a_dst,
                                                float* __restrict__ s_src,
                                                float* __restrict__ s_dst) {
    __shared__ float w1[4], w2[4];
    int node = blockIdx.x;
    int t = threadIdx.x;
    float v = hp[(size_t)node * 256 + t];
    float p1 = v * a_src[t];
    float p2 = v * a_dst[t];
    #pragma unroll
    for (int off = 32; off > 0; off >>= 1) {
        p1 += __shfl_down(p1, off, 64);
        p2 += __shfl_down(p2, off, 64);
    }
    int wave = t >> 6, lane = t & 63;
    if constexpr (NH == 4) {
        if (lane == 0) {
            s_src[node * 4 + wave] = p1;
            s_dst[node * 4 + wave] = p2;
        }
    } else {
        if (lane == 0) { w1[wave] = p1; w2[wave] = p2; }
        __syncthreads();
        if (t == 0) {
            s_src[node] = w1[0] + w1[1] + w1[2] + w1[3];
            s_dst[node] = w2[0] + w2[1] + w2[2] + w2[3];
        }
    }
}

// -------------------- softmax stats + per-edge p --------------------
// thread per (node,head): max pass, then l pass writing p=exp(ev-m) per edge
template <int NH>
__global__ __launch_bounds__(256) void softmax_stats(const float* __restrict__ ssrc,
                                                     const float* __restrict__ sdst,
                                                     const int* __restrict__ offs,
                                                     const int* __restrict__ sorted,
                                                     float* __restrict__ palpha,
                                                     float* __restrict__ linv_out,
                                                     int N) {
    int t = blockIdx.x * 256 + threadIdx.x;
    int node = t / NH, h = t % NH;
    if (node >= N) return;
    float sd = sdst[node * NH + h];
    int b = offs[node], e = offs[node + 1];
    float m = -INFINITY;
    for (int i = b; i < e; ++i) {
        float ev = ssrc[sorted[i] * NH + h] + sd;
        ev = ev > 0.f ? ev : 0.2f * ev;
        m = fmaxf(m, ev);
    }
    float l = 0.f;
    for (int i = b; i < e; ++i) {
        float ev = ssrc[sorted[i] * NH + h] + sd;
        ev = ev > 0.f ? ev : 0.2f * ev;
        float p = __expf(ev - m);
        l += p;
        palpha[(size_t)i * NH + h] = p;
    }
    linv_out[node * NH + h] = 1.0f / (l + 1e-16f);
}

// -------------------- aggregation: wave per node, float4 per lane ----------
template <int NH, bool RELU>
__global__ __launch_bounds__(256) void aggregate3(const float* __restrict__ hp,
                                                  const float* __restrict__ palpha,
                                                  const float* __restrict__ linv_arr,
                                                  const int* __restrict__ offs,
                                                  const int* __restrict__ sorted,
                                                  float* __restrict__ out, int N) {
    const int w = threadIdx.x >> 6, lane = threadIdx.x & 63;
    const int node = blockIdx.x * 4 + w;
    if (node >= N) return;
    constexpr int NF = 256 / NH;
    const int f0 = lane * 4;
    const int head = f0 / NF;
    int b = offs[node], e = offs[node + 1];
    float4 acc = make_float4(0.f, 0.f, 0.f, 0.f);
    #pragma unroll 2
    for (int i = b; i < e; ++i) {
        int s = sorted[i];
        float p = palpha[(size_t)i * NH + head];
        float4 v = *(const float4*)&hp[(size_t)s * 256 + f0];
        acc.x = fmaf(p, v.x, acc.x);
        acc.y = fmaf(p, v.y, acc.y);
        acc.z = fmaf(p, v.z, acc.z);
        acc.w = fmaf(p, v.w, acc.w);
    }
    float li = linv_arr[node * NH + head];
    float4 o = make_float4(acc.x * li, acc.y * li, acc.z * li, acc.w * li);
    if (RELU) {
        o.x = fmaxf(o.x, 0.f); o.y = fmaxf(o.y, 0.f);
        o.z = fmaxf(o.z, 0.f); o.w = fmaxf(o.w, 0.f);
    }
    *(float4*)&out[(size_t)node * 256 + f0] = o;
}

// ---------------------------------------------------------------------------
extern "C" void kernel_launch(void* const* d_in, const int* in_sizes, int n_in,
                              void* d_out, int out_size, void* d_ws, size_t ws_size,
                              hipStream_t stream) {
    const float* x   = (const float*)d_in[0];
    const int*   ei  = (const int*)d_in[1];
    const float* W1  = (const float*)d_in[2];
    const float* a1s = (const float*)d_in[3];
    const float* a1d = (const float*)d_in[4];
    const float* W2  = (const float*)d_in[5];
    const float* a2s = (const float*)d_in[6];
    const float* a2d = (const float*)d_in[7];
    float* out = (float*)d_out;

    const int N = in_sizes[0] / 256;
    const int E = in_sizes[1] / 2;
    const int* src = ei;
    const int* dst = ei + E;

    // workspace carve-up
    float* hp    = (float*)d_ws;                    // N*256
    float* ssrc  = hp + (size_t)N * 256;            // N*4
    float* sdst  = ssrc + (size_t)N * 4;            // N*4
    float* linv  = sdst + (size_t)N * 4;            // N*4
    int*   deg   = (int*)(linv + (size_t)N * 4);    // N   (aliased: deg dead after scan)
    int*   cur   = deg + N;                         // N
    int*   offs  = cur + N;                         // N+1
    int*   sorted= offs + N + 1;                    // E
    int*   bsums = sorted + E;                      // 64
    int*   boffs = bsums + 64;                      // 64
    float* palpha= (float*)(boffs + 64);            // E*4

    const int nb = (N + 1023) / 1024;

    // ---- CSR build ----
    zero_int<<<(N + 255) / 256, 256, 0, stream>>>(deg, N);
    hist_kernel<<<(E + 255) / 256, 256, 0, stream>>>(dst, deg, E);
    scan1<<<nb, 1024, 0, stream>>>(deg, offs, bsums, N);
    scan2<<<1, 1024, 0, stream>>>(bsums, boffs, offs, nb, N);
    scan3<<<nb, 1024, 0, stream>>>(offs, cur, boffs, N);
    scatter_kernel<<<(E + 255) / 256, 256, 0, stream>>>(src, dst, cur, sorted, E);

    dim3 gg((N + 63) / 64, 4);
    int aggblocks = (N + 3) / 4;

    // ---- layer 1 ----
    gemm_abt<<<gg, 256, 0, stream>>>(x, W1, hp, N);
    scompute<4><<<N, 256, 0, stream>>>(hp, a1s, a1d, ssrc, sdst);
    softmax_stats<4><<<(N * 4 + 255) / 256, 256, 0, stream>>>(ssrc, sdst, offs, sorted, palpha, linv, N);
    aggregate3<4, true><<<aggblocks, 256, 0, stream>>>(hp, palpha, linv, offs, sorted, out, N);

    // ---- layer 2 (h lives in d_out; dead before final aggregate overwrites) ----
    gemm_abt<<<gg, 256, 0, stream>>>(out, W2, hp, N);
    scompute<1><<<N, 256, 0, stream>>>(hp, a2s, a2d, ssrc, sdst);
    softmax_stats<1><<<(N + 255) / 256, 256, 0, stream>>>(ssrc, sdst, offs, sorted, palpha, linv, N);
    aggregate3<1, false><<<aggblocks, 256, 0, stream>>>(hp, palpha, linv, offs, sorted, out, N);
}

// Round 4
// 612.535 us; speedup vs baseline: 1.5022x; 1.2035x over previous
//
#include <hip/hip_runtime.h>
#include <math.h>

// ---------------------------------------------------------------------------
// GAT 2-layer pipeline for MI355X.
// N=50000 nodes, E=850000 edges (incl self loops), feat 256, H=4 x 64 -> 256.
//
//   CSR build: zero, hist, two-level scan, scatter
//   convert_w: W -> (Whi, Wlo) bf16 split (once per launch, tiny)
//   gemm_mfma: C = A @ W^T via split-bf16 3-pass MFMA (A split inline in staging)
//   scompute / softmax_stats / aggregate3 as round 3
// ---------------------------------------------------------------------------

typedef __attribute__((ext_vector_type(8))) short short8;   // 8 x bf16
typedef __attribute__((ext_vector_type(4))) float f32x4;    // MFMA acc

__device__ inline short f2bf(float f) {
    unsigned u = __float_as_uint(f);
    unsigned r = (u + 0x7FFF + ((u >> 16) & 1)) >> 16;  // RN-even
    return (short)r;
}
__device__ inline float bf2f(short b) {
    return __uint_as_float(((unsigned)(unsigned short)b) << 16);
}

__global__ void convert_w(const float* __restrict__ W, short* __restrict__ Whi,
                          short* __restrict__ Wlo, int n) {
    int i = blockIdx.x * 256 + threadIdx.x;
    if (i < n) {
        float v = W[i];
        short h = f2bf(v);
        Whi[i] = h;
        Wlo[i] = f2bf(v - bf2f(h));
    }
}

// C[M x 256] = A[M x 256] @ B^T, B = [256 x 256] given as bf16 hi/lo pair.
// grid (ceil(M/64), 2), block 256 (4 waves). Tile 64x128, BK=32.
// LDS rows padded to 40 bf16 (80 B): frag-read bank stride 20 -> 2-way (free).
__global__ __launch_bounds__(256) void gemm_mfma(const float* __restrict__ A,
                                                 const short* __restrict__ Bh_g,
                                                 const short* __restrict__ Bl_g,
                                                 float* __restrict__ C, int M) {
    __shared__ short Ah[64 * 40];
    __shared__ short Al[64 * 40];
    __shared__ short Bh[128 * 40];
    __shared__ short Bl[128 * 40];
    const int tid = threadIdx.x;
    const int m0 = blockIdx.x * 64;
    const int n0 = blockIdx.y * 128;
    const int w = tid >> 6, lane = tid & 63;
    const int l15 = lane & 15, q = lane >> 4;

    f32x4 acc[8];
    #pragma unroll
    for (int i = 0; i < 8; ++i) acc[i] = (f32x4){0.f, 0.f, 0.f, 0.f};

    // staging maps
    const int ar = tid >> 2;          // A row 0..63
    const int ak = (tid & 3) * 8;     // A k-offset 0/8/16/24
    const int br = tid >> 1;          // B row 0..127
    const int bk = (tid & 1) * 16;    // B k-offset 0/16

    for (int k0 = 0; k0 < 256; k0 += 32) {
        // ---- A stage: 8 fp32 -> hi/lo bf16x8 (split computed in-register) ----
        int gm = m0 + ar;
        float4 v0, v1;
        if (gm < M) {
            v0 = *(const float4*)&A[(size_t)gm * 256 + k0 + ak];
            v1 = *(const float4*)&A[(size_t)gm * 256 + k0 + ak + 4];
        } else {
            v0 = make_float4(0.f, 0.f, 0.f, 0.f);
            v1 = v0;
        }
        float av[8] = {v0.x, v0.y, v0.z, v0.w, v1.x, v1.y, v1.z, v1.w};
        short8 hi, lo;
        #pragma unroll
        for (int j = 0; j < 8; ++j) {
            short h = f2bf(av[j]);
            hi[j] = h;
            lo[j] = f2bf(av[j] - bf2f(h));
        }
        *(short8*)&Ah[ar * 40 + ak] = hi;
        *(short8*)&Al[ar * 40 + ak] = lo;
        // ---- B stage: pre-split bf16, 2 x 16B per matrix ----
        {
            const short* s0 = &Bh_g[(size_t)(n0 + br) * 256 + k0 + bk];
            *(short8*)&Bh[br * 40 + bk]     = *(const short8*)s0;
            *(short8*)&Bh[br * 40 + bk + 8] = *(const short8*)(s0 + 8);
            const short* s1 = &Bl_g[(size_t)(n0 + br) * 256 + k0 + bk];
            *(short8*)&Bl[br * 40 + bk]     = *(const short8*)s1;
            *(short8*)&Bl[br * 40 + bk + 8] = *(const short8*)(s1 + 8);
        }
        __syncthreads();
        // ---- compute: wave w covers rows w*16..w*16+15, all 128 cols ----
        int rowA = w * 16 + l15;
        short8 ahi = *(short8*)&Ah[rowA * 40 + q * 8];
        short8 alo = *(short8*)&Al[rowA * 40 + q * 8];
        #pragma unroll
        for (int nt = 0; nt < 8; ++nt) {
            int rowB = nt * 16 + l15;
            short8 bhi = *(short8*)&Bh[rowB * 40 + q * 8];
            short8 blo = *(short8*)&Bl[rowB * 40 + q * 8];
            acc[nt] = __builtin_amdgcn_mfma_f32_16x16x32_bf16(ahi, bhi, acc[nt], 0, 0, 0);
            acc[nt] = __builtin_amdgcn_mfma_f32_16x16x32_bf16(alo, bhi, acc[nt], 0, 0, 0);
            acc[nt] = __builtin_amdgcn_mfma_f32_16x16x32_bf16(ahi, blo, acc[nt], 0, 0, 0);
        }
        __syncthreads();
    }
    // epilogue: C/D layout col=lane&15, row=quad*4+reg (verified m89/m91)
    #pragma unroll
    for (int nt = 0; nt < 8; ++nt) {
        #pragma unroll
        for (int r = 0; r < 4; ++r) {
            int gm = m0 + w * 16 + q * 4 + r;
            if (gm < M) C[(size_t)gm * 256 + n0 + nt * 16 + l15] = acc[nt][r];
        }
    }
}

// -------------------- CSR build --------------------
__global__ void zero_int(int* __restrict__ p, int n) {
    int i = blockIdx.x * 256 + threadIdx.x;
    if (i < n) p[i] = 0;
}

__global__ void hist_kernel(const int* __restrict__ dst, int* __restrict__ deg, int E) {
    int i = blockIdx.x * 256 + threadIdx.x;
    if (i < E) atomicAdd(&deg[dst[i]], 1);
}

__global__ __launch_bounds__(1024) void scan1(const int* __restrict__ deg,
                                              int* __restrict__ lex,
                                              int* __restrict__ bsums, int n) {
    __shared__ int sh[1024];
    int tid = threadIdx.x;
    int i = blockIdx.x * 1024 + tid;
    int v = (i < n) ? deg[i] : 0;
    sh[tid] = v;
    __syncthreads();
    #pragma unroll
    for (int off = 1; off < 1024; off <<= 1) {
        int t2 = (tid >= off) ? sh[tid - off] : 0;
        __syncthreads();
        sh[tid] += t2;
        __syncthreads();
    }
    if (i < n) lex[i] = sh[tid] - v;
    if (tid == 1023) bsums[blockIdx.x] = sh[1023];
}

__global__ __launch_bounds__(1024) void scan2(const int* __restrict__ bsums,
                                              int* __restrict__ boffs,
                                              int* __restrict__ offs, int nb, int n) {
    __shared__ int sh[1024];
    int tid = threadIdx.x;
    int v = (tid < nb) ? bsums[tid] : 0;
    sh[tid] = v;
    __syncthreads();
    #pragma unroll
    for (int off = 1; off < 1024; off <<= 1) {
        int t2 = (tid >= off) ? sh[tid - off] : 0;
        __syncthreads();
        sh[tid] += t2;
        __syncthreads();
    }
    if (tid < nb) boffs[tid] = sh[tid] - v;
    if (tid == nb - 1) offs[n] = sh[tid];
}

__global__ __launch_bounds__(1024) void scan3(int* __restrict__ offs,
                                              int* __restrict__ cur,
                                              const int* __restrict__ boffs, int n) {
    int i = blockIdx.x * 1024 + threadIdx.x;
    if (i < n) {
        int o = offs[i] + boffs[blockIdx.x];
        offs[i] = o;
        cur[i] = o;
    }
}

__global__ void scatter_kernel(const int* __restrict__ src, const int* __restrict__ dst,
                               int* __restrict__ cur, int* __restrict__ sorted, int E) {
    int i = blockIdx.x * 256 + threadIdx.x;
    if (i < E) {
        int p = atomicAdd(&cur[dst[i]], 1);
        sorted[p] = src[i];
    }
}

// -------------------- attention scalars --------------------
template <int NH>
__global__ __launch_bounds__(256) void scompute(const float* __restrict__ hp,
                                                const float* __restrict__ a_src,
                                                const float* __restrict__ a_dst,
                                                float* __restrict__ s_src,
                                                float* __restrict__ s_dst) {
    __shared__ float w1[4], w2[4];
    int node = blockIdx.x;
    int t = threadIdx.x;
    float v = hp[(size_t)node * 256 + t];
    float p1 = v * a_src[t];
    float p2 = v * a_dst[t];
    #pragma unroll
    for (int off = 32; off > 0; off >>= 1) {
        p1 += __shfl_down(p1, off, 64);
        p2 += __shfl_down(p2, off, 64);
    }
    int wave = t >> 6, lane = t & 63;
    if constexpr (NH == 4) {
        if (lane == 0) {
            s_src[node * 4 + wave] = p1;
            s_dst[node * 4 + wave] = p2;
        }
    } else {
        if (lane == 0) { w1[wave] = p1; w2[wave] = p2; }
        __syncthreads();
        if (t == 0) {
            s_src[node] = w1[0] + w1[1] + w1[2] + w1[3];
            s_dst[node] = w2[0] + w2[1] + w2[2] + w2[3];
        }
    }
}

// -------------------- softmax stats + per-edge p --------------------
template <int NH>
__global__ __launch_bounds__(256) void softmax_stats(const float* __restrict__ ssrc,
                                                     const float* __restrict__ sdst,
                                                     const int* __restrict__ offs,
                                                     const int* __restrict__ sorted,
                                                     float* __restrict__ palpha,
                                                     float* __restrict__ linv_out,
                                                     int N) {
    int t = blockIdx.x * 256 + threadIdx.x;
    int node = t / NH, h = t % NH;
    if (node >= N) return;
    float sd = sdst[node * NH + h];
    int b = offs[node], e = offs[node + 1];
    float m = -INFINITY;
    for (int i = b; i < e; ++i) {
        float ev = ssrc[sorted[i] * NH + h] + sd;
        ev = ev > 0.f ? ev : 0.2f * ev;
        m = fmaxf(m, ev);
    }
    float l = 0.f;
    for (int i = b; i < e; ++i) {
        float ev = ssrc[sorted[i] * NH + h] + sd;
        ev = ev > 0.f ? ev : 0.2f * ev;
        float p = __expf(ev - m);
        l += p;
        palpha[(size_t)i * NH + h] = p;
    }
    linv_out[node * NH + h] = 1.0f / (l + 1e-16f);
}

// -------------------- aggregation: wave per node, float4 per lane ----------
template <int NH, bool RELU>
__global__ __launch_bounds__(256) void aggregate3(const float* __restrict__ hp,
                                                  const float* __restrict__ palpha,
                                                  const float* __restrict__ linv_arr,
                                                  const int* __restrict__ offs,
                                                  const int* __restrict__ sorted,
                                                  float* __restrict__ out, int N) {
    const int w = threadIdx.x >> 6, lane = threadIdx.x & 63;
    const int node = blockIdx.x * 4 + w;
    if (node >= N) return;
    constexpr int NF = 256 / NH;
    const int f0 = lane * 4;
    const int head = f0 / NF;
    int b = offs[node], e = offs[node + 1];
    float4 acc = make_float4(0.f, 0.f, 0.f, 0.f);
    #pragma unroll 2
    for (int i = b; i < e; ++i) {
        int s = sorted[i];
        float p = palpha[(size_t)i * NH + head];
        float4 v = *(const float4*)&hp[(size_t)s * 256 + f0];
        acc.x = fmaf(p, v.x, acc.x);
        acc.y = fmaf(p, v.y, acc.y);
        acc.z = fmaf(p, v.z, acc.z);
        acc.w = fmaf(p, v.w, acc.w);
    }
    float li = linv_arr[node * NH + head];
    float4 o = make_float4(acc.x * li, acc.y * li, acc.z * li, acc.w * li);
    if (RELU) {
        o.x = fmaxf(o.x, 0.f); o.y = fmaxf(o.y, 0.f);
        o.z = fmaxf(o.z, 0.f); o.w = fmaxf(o.w, 0.f);
    }
    *(float4*)&out[(size_t)node * 256 + f0] = o;
}

// ---------------------------------------------------------------------------
extern "C" void kernel_launch(void* const* d_in, const int* in_sizes, int n_in,
                              void* d_out, int out_size, void* d_ws, size_t ws_size,
                              hipStream_t stream) {
    const float* x   = (const float*)d_in[0];
    const int*   ei  = (const int*)d_in[1];
    const float* W1  = (const float*)d_in[2];
    const float* a1s = (const float*)d_in[3];
    const float* a1d = (const float*)d_in[4];
    const float* W2  = (const float*)d_in[5];
    const float* a2s = (const float*)d_in[6];
    const float* a2d = (const float*)d_in[7];
    float* out = (float*)d_out;

    const int N = in_sizes[0] / 256;
    const int E = in_sizes[1] / 2;
    const int* src = ei;
    const int* dst = ei + E;

    // workspace carve-up
    float* hp    = (float*)d_ws;                    // N*256
    float* ssrc  = hp + (size_t)N * 256;            // N*4
    float* sdst  = ssrc + (size_t)N * 4;            // N*4
    float* linv  = sdst + (size_t)N * 4;            // N*4
    int*   deg   = (int*)(linv + (size_t)N * 4);    // N
    int*   cur   = deg + N;                         // N
    int*   offs  = cur + N;                         // N+1
    int*   sorted= offs + N + 1;                    // E
    int*   bsums = sorted + E;                      // 64
    int*   boffs = bsums + 64;                      // 64
    float* palpha= (float*)(boffs + 64);            // E*4
    short* w1hi  = (short*)(palpha + (size_t)E * 4);// 65536
    short* w1lo  = w1hi + 65536;
    short* w2hi  = w1lo + 65536;
    short* w2lo  = w2hi + 65536;

    const int nb = (N + 1023) / 1024;

    // ---- weight split (tiny; every call, no static guards) ----
    convert_w<<<256, 256, 0, stream>>>(W1, w1hi, w1lo, 65536);
    convert_w<<<256, 256, 0, stream>>>(W2, w2hi, w2lo, 65536);

    // ---- CSR build ----
    zero_int<<<(N + 255) / 256, 256, 0, stream>>>(deg, N);
    hist_kernel<<<(E + 255) / 256, 256, 0, stream>>>(dst, deg, E);
    scan1<<<nb, 1024, 0, stream>>>(deg, offs, bsums, N);
    scan2<<<1, 1024, 0, stream>>>(bsums, boffs, offs, nb, N);
    scan3<<<nb, 1024, 0, stream>>>(offs, cur, boffs, N);
    scatter_kernel<<<(E + 255) / 256, 256, 0, stream>>>(src, dst, cur, sorted, E);

    dim3 gg((N + 63) / 64, 2);
    int aggblocks = (N + 3) / 4;

    // ---- layer 1 ----
    gemm_mfma<<<gg, 256, 0, stream>>>(x, w1hi, w1lo, hp, N);
    scompute<4><<<N, 256, 0, stream>>>(hp, a1s, a1d, ssrc, sdst);
    softmax_stats<4><<<(N * 4 + 255) / 256, 256, 0, stream>>>(ssrc, sdst, offs, sorted, palpha, linv, N);
    aggregate3<4, true><<<aggblocks, 256, 0, stream>>>(hp, palpha, linv, offs, sorted, out, N);

    // ---- layer 2 (h lives in d_out; dead before final aggregate overwrites) ----
    gemm_mfma<<<gg, 256, 0, stream>>>(out, w2hi, w2lo, hp, N);
    scompute<1><<<N, 256, 0, stream>>>(hp, a2s, a2d, ssrc, sdst);
    softmax_stats<1><<<(N + 255) / 256, 256, 0, stream>>>(ssrc, sdst, offs, sorted, palpha, linv, N);
    aggregate3<1, false><<<aggblocks, 256, 0, stream>>>(hp, palpha, linv, offs, sorted, out, N);
}

// Round 5
// 513.547 us; speedup vs baseline: 1.7918x; 1.1928x over previous
//
#include <hip/hip_runtime.h>
#include <math.h>

// ---------------------------------------------------------------------------
// GAT 2-layer pipeline for MI355X.
// N=50000 nodes, E=850000 edges (incl self loops), feat 256, H=4 x 64 -> 256.
//
//   CSR build: zero, hist, two-level scan, scatter
//   convert_w: W -> (Whi, Wlo) bf16 split
//   gemm_mfma: C = A @ W^T via split-bf16 3-pass MFMA; writes hp as FP16
//   scompute (fp16 in) / softmax_stats / aggregate3 (fp16 gather)
// ---------------------------------------------------------------------------

typedef __attribute__((ext_vector_type(8))) short short8;          // 8 x bf16
typedef __attribute__((ext_vector_type(4))) float f32x4;           // MFMA acc
typedef __attribute__((ext_vector_type(4))) unsigned short us4;    // 4 x fp16

__device__ inline short f2bf(float f) {
    unsigned u = __float_as_uint(f);
    unsigned r = (u + 0x7FFF + ((u >> 16) & 1)) >> 16;  // RN-even
    return (short)r;
}
__device__ inline float bf2f(short b) {
    return __uint_as_float(((unsigned)(unsigned short)b) << 16);
}
__device__ inline unsigned short f2h(float f) {
    _Float16 h = (_Float16)f;
    unsigned short u;
    __builtin_memcpy(&u, &h, 2);
    return u;
}
__device__ inline float h2f(unsigned short u) {
    _Float16 h;
    __builtin_memcpy(&h, &u, 2);
    return (float)h;
}

__global__ void convert_w(const float* __restrict__ W, short* __restrict__ Whi,
                          short* __restrict__ Wlo, int n) {
    int i = blockIdx.x * 256 + threadIdx.x;
    if (i < n) {
        float v = W[i];
        short h = f2bf(v);
        Whi[i] = h;
        Wlo[i] = f2bf(v - bf2f(h));
    }
}

// C[M x 256] (FP16) = A[M x 256] (fp32) @ B^T, B as bf16 hi/lo pair.
// grid (ceil(M/64), 2), block 256 (4 waves). Tile 64x128, BK=32.
__global__ __launch_bounds__(256) void gemm_mfma(const float* __restrict__ A,
                                                 const short* __restrict__ Bh_g,
                                                 const short* __restrict__ Bl_g,
                                                 unsigned short* __restrict__ C, int M) {
    __shared__ short Ah[64 * 40];
    __shared__ short Al[64 * 40];
    __shared__ short Bh[128 * 40];
    __shared__ short Bl[128 * 40];
    const int tid = threadIdx.x;
    const int m0 = blockIdx.x * 64;
    const int n0 = blockIdx.y * 128;
    const int w = tid >> 6, lane = tid & 63;
    const int l15 = lane & 15, q = lane >> 4;

    f32x4 acc[8];
    #pragma unroll
    for (int i = 0; i < 8; ++i) acc[i] = (f32x4){0.f, 0.f, 0.f, 0.f};

    const int ar = tid >> 2;          // A row 0..63
    const int ak = (tid & 3) * 8;     // A k-offset 0/8/16/24
    const int br = tid >> 1;          // B row 0..127
    const int bk = (tid & 1) * 16;    // B k-offset 0/16

    for (int k0 = 0; k0 < 256; k0 += 32) {
        int gm = m0 + ar;
        float4 v0, v1;
        if (gm < M) {
            v0 = *(const float4*)&A[(size_t)gm * 256 + k0 + ak];
            v1 = *(const float4*)&A[(size_t)gm * 256 + k0 + ak + 4];
        } else {
            v0 = make_float4(0.f, 0.f, 0.f, 0.f);
            v1 = v0;
        }
        float av[8] = {v0.x, v0.y, v0.z, v0.w, v1.x, v1.y, v1.z, v1.w};
        short8 hi, lo;
        #pragma unroll
        for (int j = 0; j < 8; ++j) {
            short h = f2bf(av[j]);
            hi[j] = h;
            lo[j] = f2bf(av[j] - bf2f(h));
        }
        *(short8*)&Ah[ar * 40 + ak] = hi;
        *(short8*)&Al[ar * 40 + ak] = lo;
        {
            const short* s0 = &Bh_g[(size_t)(n0 + br) * 256 + k0 + bk];
            *(short8*)&Bh[br * 40 + bk]     = *(const short8*)s0;
            *(short8*)&Bh[br * 40 + bk + 8] = *(const short8*)(s0 + 8);
            const short* s1 = &Bl_g[(size_t)(n0 + br) * 256 + k0 + bk];
            *(short8*)&Bl[br * 40 + bk]     = *(const short8*)s1;
            *(short8*)&Bl[br * 40 + bk + 8] = *(const short8*)(s1 + 8);
        }
        __syncthreads();
        int rowA = w * 16 + l15;
        short8 ahi = *(short8*)&Ah[rowA * 40 + q * 8];
        short8 alo = *(short8*)&Al[rowA * 40 + q * 8];
        #pragma unroll
        for (int nt = 0; nt < 8; ++nt) {
            int rowB = nt * 16 + l15;
            short8 bhi = *(short8*)&Bh[rowB * 40 + q * 8];
            short8 blo = *(short8*)&Bl[rowB * 40 + q * 8];
            acc[nt] = __builtin_amdgcn_mfma_f32_16x16x32_bf16(ahi, bhi, acc[nt], 0, 0, 0);
            acc[nt] = __builtin_amdgcn_mfma_f32_16x16x32_bf16(alo, bhi, acc[nt], 0, 0, 0);
            acc[nt] = __builtin_amdgcn_mfma_f32_16x16x32_bf16(ahi, blo, acc[nt], 0, 0, 0);
        }
        __syncthreads();
    }
    // epilogue: C/D layout col=lane&15, row=quad*4+reg
    #pragma unroll
    for (int nt = 0; nt < 8; ++nt) {
        #pragma unroll
        for (int r = 0; r < 4; ++r) {
            int gm = m0 + w * 16 + q * 4 + r;
            if (gm < M) C[(size_t)gm * 256 + n0 + nt * 16 + l15] = f2h(acc[nt][r]);
        }
    }
}

// -------------------- CSR build --------------------
__global__ void zero_int(int* __restrict__ p, int n) {
    int i = blockIdx.x * 256 + threadIdx.x;
    if (i < n) p[i] = 0;
}

__global__ void hist_kernel(const int* __restrict__ dst, int* __restrict__ deg, int E) {
    int i = blockIdx.x * 256 + threadIdx.x;
    if (i < E) atomicAdd(&deg[dst[i]], 1);
}

__global__ __launch_bounds__(1024) void scan1(const int* __restrict__ deg,
                                              int* __restrict__ lex,
                                              int* __restrict__ bsums, int n) {
    __shared__ int sh[1024];
    int tid = threadIdx.x;
    int i = blockIdx.x * 1024 + tid;
    int v = (i < n) ? deg[i] : 0;
    sh[tid] = v;
    __syncthreads();
    #pragma unroll
    for (int off = 1; off < 1024; off <<= 1) {
        int t2 = (tid >= off) ? sh[tid - off] : 0;
        __syncthreads();
        sh[tid] += t2;
        __syncthreads();
    }
    if (i < n) lex[i] = sh[tid] - v;
    if (tid == 1023) bsums[blockIdx.x] = sh[1023];
}

__global__ __launch_bounds__(1024) void scan2(const int* __restrict__ bsums,
                                              int* __restrict__ boffs,
                                              int* __restrict__ offs, int nb, int n) {
    __shared__ int sh[1024];
    int tid = threadIdx.x;
    int v = (tid < nb) ? bsums[tid] : 0;
    sh[tid] = v;
    __syncthreads();
    #pragma unroll
    for (int off = 1; off < 1024; off <<= 1) {
        int t2 = (tid >= off) ? sh[tid - off] : 0;
        __syncthreads();
        sh[tid] += t2;
        __syncthreads();
    }
    if (tid < nb) boffs[tid] = sh[tid] - v;
    if (tid == nb - 1) offs[n] = sh[tid];
}

__global__ __launch_bounds__(1024) void scan3(int* __restrict__ offs,
                                              int* __restrict__ cur,
                                              const int* __restrict__ boffs, int n) {
    int i = blockIdx.x * 1024 + threadIdx.x;
    if (i < n) {
        int o = offs[i] + boffs[blockIdx.x];
        offs[i] = o;
        cur[i] = o;
    }
}

__global__ void scatter_kernel(const int* __restrict__ src, const int* __restrict__ dst,
                               int* __restrict__ cur, int* __restrict__ sorted, int E) {
    int i = blockIdx.x * 256 + threadIdx.x;
    if (i < E) {
        int p = atomicAdd(&cur[dst[i]], 1);
        sorted[p] = src[i];
    }
}

// -------------------- attention scalars (fp16 hp in) --------------------
template <int NH>
__global__ __launch_bounds__(256) void scompute(const unsigned short* __restrict__ hp,
                                                const float* __restrict__ a_src,
                                                const float* __restrict__ a_dst,
                                                float* __restrict__ s_src,
                                                float* __restrict__ s_dst) {
    __shared__ float w1[4], w2[4];
    int node = blockIdx.x;
    int t = threadIdx.x;
    float v = h2f(hp[(size_t)node * 256 + t]);
    float p1 = v * a_src[t];
    float p2 = v * a_dst[t];
    #pragma unroll
    for (int off = 32; off > 0; off >>= 1) {
        p1 += __shfl_down(p1, off, 64);
        p2 += __shfl_down(p2, off, 64);
    }
    int wave = t >> 6, lane = t & 63;
    if constexpr (NH == 4) {
        if (lane == 0) {
            s_src[node * 4 + wave] = p1;
            s_dst[node * 4 + wave] = p2;
        }
    } else {
        if (lane == 0) { w1[wave] = p1; w2[wave] = p2; }
        __syncthreads();
        if (t == 0) {
            s_src[node] = w1[0] + w1[1] + w1[2] + w1[3];
            s_dst[node] = w2[0] + w2[1] + w2[2] + w2[3];
        }
    }
}

// -------------------- softmax stats + per-edge p --------------------
template <int NH>
__global__ __launch_bounds__(256) void softmax_stats(const float* __restrict__ ssrc,
                                                     const float* __restrict__ sdst,
                                                     const int* __restrict__ offs,
                                                     const int* __restrict__ sorted,
                                                     float* __restrict__ palpha,
                                                     float* __restrict__ linv_out,
                                                     int N) {
    int t = blockIdx.x * 256 + threadIdx.x;
    int node = t / NH, h = t % NH;
    if (node >= N) return;
    float sd = sdst[node * NH + h];
    int b = offs[node], e = offs[node + 1];
    float m = -INFINITY;
    for (int i = b; i < e; ++i) {
        float ev = ssrc[sorted[i] * NH + h] + sd;
        ev = ev > 0.f ? ev : 0.2f * ev;
        m = fmaxf(m, ev);
    }
    float l = 0.f;
    for (int i = b; i < e; ++i) {
        float ev = ssrc[sorted[i] * NH + h] + sd;
        ev = ev > 0.f ? ev : 0.2f * ev;
        float p = __expf(ev - m);
        l += p;
        palpha[(size_t)i * NH + h] = p;
    }
    linv_out[node * NH + h] = 1.0f / (l + 1e-16f);
}

// -------------------- aggregation: wave/node, fp16 gather, 4 feat/lane -----
template <int NH, bool RELU>
__global__ __launch_bounds__(256) void aggregate3(const unsigned short* __restrict__ hp,
                                                  const float* __restrict__ palpha,
                                                  const float* __restrict__ linv_arr,
                                                  const int* __restrict__ offs,
                                                  const int* __restrict__ sorted,
                                                  float* __restrict__ out, int N) {
    const int w = threadIdx.x >> 6, lane = threadIdx.x & 63;
    const int node = blockIdx.x * 4 + w;
    if (node >= N) return;
    constexpr int NF = 256 / NH;
    const int f0 = lane * 4;
    const int head = f0 / NF;
    int b = offs[node], e = offs[node + 1];
    float4 acc = make_float4(0.f, 0.f, 0.f, 0.f);
    #pragma unroll 2
    for (int i = b; i < e; ++i) {
        int s = sorted[i];
        float p = palpha[(size_t)i * NH + head];
        us4 v = *(const us4*)&hp[(size_t)s * 256 + f0];
        acc.x = fmaf(p, h2f(v[0]), acc.x);
        acc.y = fmaf(p, h2f(v[1]), acc.y);
        acc.z = fmaf(p, h2f(v[2]), acc.z);
        acc.w = fmaf(p, h2f(v[3]), acc.w);
    }
    float li = linv_arr[node * NH + head];
    float4 o = make_float4(acc.x * li, acc.y * li, acc.z * li, acc.w * li);
    if (RELU) {
        o.x = fmaxf(o.x, 0.f); o.y = fmaxf(o.y, 0.f);
        o.z = fmaxf(o.z, 0.f); o.w = fmaxf(o.w, 0.f);
    }
    *(float4*)&out[(size_t)node * 256 + f0] = o;
}

// ---------------------------------------------------------------------------
extern "C" void kernel_launch(void* const* d_in, const int* in_sizes, int n_in,
                              void* d_out, int out_size, void* d_ws, size_t ws_size,
                              hipStream_t stream) {
    const float* x   = (const float*)d_in[0];
    const int*   ei  = (const int*)d_in[1];
    const float* W1  = (const float*)d_in[2];
    const float* a1s = (const float*)d_in[3];
    const float* a1d = (const float*)d_in[4];
    const float* W2  = (const float*)d_in[5];
    const float* a2s = (const float*)d_in[6];
    const float* a2d = (const float*)d_in[7];
    float* out = (float*)d_out;

    const int N = in_sizes[0] / 256;
    const int E = in_sizes[1] / 2;
    const int* src = ei;
    const int* dst = ei + E;

    // workspace carve-up
    unsigned short* hp = (unsigned short*)d_ws;     // N*256 fp16
    float* ssrc  = (float*)(hp + (size_t)N * 256);  // N*4
    float* sdst  = ssrc + (size_t)N * 4;            // N*4
    float* linv  = sdst + (size_t)N * 4;            // N*4
    int*   deg   = (int*)(linv + (size_t)N * 4);    // N
    int*   cur   = deg + N;                         // N
    int*   offs  = cur + N;                         // N+1
    int*   sorted= offs + N + 1;                    // E
    int*   bsums = sorted + E;                      // 64
    int*   boffs = bsums + 64;                      // 64
    float* palpha= (float*)(boffs + 64);            // E*4
    short* w1hi  = (short*)(palpha + (size_t)E * 4);// 65536
    short* w1lo  = w1hi + 65536;
    short* w2hi  = w1lo + 65536;
    short* w2lo  = w2hi + 65536;

    const int nb = (N + 1023) / 1024;

    // ---- weight split ----
    convert_w<<<256, 256, 0, stream>>>(W1, w1hi, w1lo, 65536);
    convert_w<<<256, 256, 0, stream>>>(W2, w2hi, w2lo, 65536);

    // ---- CSR build ----
    zero_int<<<(N + 255) / 256, 256, 0, stream>>>(deg, N);
    hist_kernel<<<(E + 255) / 256, 256, 0, stream>>>(dst, deg, E);
    scan1<<<nb, 1024, 0, stream>>>(deg, offs, bsums, N);
    scan2<<<1, 1024, 0, stream>>>(bsums, boffs, offs, nb, N);
    scan3<<<nb, 1024, 0, stream>>>(offs, cur, boffs, N);
    scatter_kernel<<<(E + 255) / 256, 256, 0, stream>>>(src, dst, cur, sorted, E);

    dim3 gg((N + 63) / 64, 2);
    int aggblocks = (N + 3) / 4;

    // ---- layer 1 ----
    gemm_mfma<<<gg, 256, 0, stream>>>(x, w1hi, w1lo, hp, N);
    scompute<4><<<N, 256, 0, stream>>>(hp, a1s, a1d, ssrc, sdst);
    softmax_stats<4><<<(N * 4 + 255) / 256, 256, 0, stream>>>(ssrc, sdst, offs, sorted, palpha, linv, N);
    aggregate3<4, true><<<aggblocks, 256, 0, stream>>>(hp, palpha, linv, offs, sorted, out, N);

    // ---- layer 2 (h in d_out fp32; dead before final aggregate overwrites) ----
    gemm_mfma<<<gg, 256, 0, stream>>>(out, w2hi, w2lo, hp, N);
    scompute<1><<<N, 256, 0, stream>>>(hp, a2s, a2d, ssrc, sdst);
    softmax_stats<1><<<(N + 255) / 256, 256, 0, stream>>>(ssrc, sdst, offs, sorted, palpha, linv, N);
    aggregate3<1, false><<<aggblocks, 256, 0, stream>>>(hp, palpha, linv, offs, sorted, out, N);
}

// Round 7
// 453.408 us; speedup vs baseline: 2.0294x; 1.1326x over previous
//
#include <hip/hip_runtime.h>
#include <math.h>

// ---------------------------------------------------------------------------
// GAT 2-layer pipeline for MI355X.
// N=50000 nodes, E=850000 edges (incl self loops), feat 256, H=4 x 64 -> 256.
//
//   CSR build: zero, hist, two-level scan, scatter
//   convert_w: W -> (Whi, Wlo) bf16 split
//   gemm_mfma: C = A @ W^T via split-bf16 3-pass MFMA; writes hp as FP16
//   scompute (fp16 in)
//   aggregate4: wave-per-node FUSED softmax-stats + gather-aggregate.
//     NOTE: main loop trip count is wave-uniform (pairs = ceil(deg/2)) so every
//     __shfl executes with all 64 lanes active — ds_bpermute reads from
//     exec-masked lanes are undefined (caused round-6 absmax failure on
//     odd-degree >=33 nodes).
// ---------------------------------------------------------------------------

typedef __attribute__((ext_vector_type(8))) short short8;          // 8 x bf16
typedef __attribute__((ext_vector_type(4))) float f32x4;           // MFMA acc
typedef _Float16 half8 __attribute__((ext_vector_type(8)));        // 8 x fp16

__device__ inline short f2bf(float f) {
    unsigned u = __float_as_uint(f);
    unsigned r = (u + 0x7FFF + ((u >> 16) & 1)) >> 16;  // RN-even
    return (short)r;
}
__device__ inline float bf2f(short b) {
    return __uint_as_float(((unsigned)(unsigned short)b) << 16);
}
__device__ inline unsigned short f2h(float f) {
    _Float16 h = (_Float16)f;
    unsigned short u;
    __builtin_memcpy(&u, &h, 2);
    return u;
}
__device__ inline float h2f(unsigned short u) {
    _Float16 h;
    __builtin_memcpy(&h, &u, 2);
    return (float)h;
}

__global__ void convert_w(const float* __restrict__ W, short* __restrict__ Whi,
                          short* __restrict__ Wlo, int n) {
    int i = blockIdx.x * 256 + threadIdx.x;
    if (i < n) {
        float v = W[i];
        short h = f2bf(v);
        Whi[i] = h;
        Wlo[i] = f2bf(v - bf2f(h));
    }
}

// C[M x 256] (FP16) = A[M x 256] (fp32) @ B^T, B as bf16 hi/lo pair.
__global__ __launch_bounds__(256) void gemm_mfma(const float* __restrict__ A,
                                                 const short* __restrict__ Bh_g,
                                                 const short* __restrict__ Bl_g,
                                                 unsigned short* __restrict__ C, int M) {
    __shared__ short Ah[64 * 40];
    __shared__ short Al[64 * 40];
    __shared__ short Bh[128 * 40];
    __shared__ short Bl[128 * 40];
    const int tid = threadIdx.x;
    const int m0 = blockIdx.x * 64;
    const int n0 = blockIdx.y * 128;
    const int w = tid >> 6, lane = tid & 63;
    const int l15 = lane & 15, q = lane >> 4;

    f32x4 acc[8];
    #pragma unroll
    for (int i = 0; i < 8; ++i) acc[i] = (f32x4){0.f, 0.f, 0.f, 0.f};

    const int ar = tid >> 2;
    const int ak = (tid & 3) * 8;
    const int br = tid >> 1;
    const int bk = (tid & 1) * 16;

    for (int k0 = 0; k0 < 256; k0 += 32) {
        int gm = m0 + ar;
        float4 v0, v1;
        if (gm < M) {
            v0 = *(const float4*)&A[(size_t)gm * 256 + k0 + ak];
            v1 = *(const float4*)&A[(size_t)gm * 256 + k0 + ak + 4];
        } else {
            v0 = make_float4(0.f, 0.f, 0.f, 0.f);
            v1 = v0;
        }
        float av[8] = {v0.x, v0.y, v0.z, v0.w, v1.x, v1.y, v1.z, v1.w};
        short8 hi, lo;
        #pragma unroll
        for (int j = 0; j < 8; ++j) {
            short h = f2bf(av[j]);
            hi[j] = h;
            lo[j] = f2bf(av[j] - bf2f(h));
        }
        *(short8*)&Ah[ar * 40 + ak] = hi;
        *(short8*)&Al[ar * 40 + ak] = lo;
        {
            const short* s0 = &Bh_g[(size_t)(n0 + br) * 256 + k0 + bk];
            *(short8*)&Bh[br * 40 + bk]     = *(const short8*)s0;
            *(short8*)&Bh[br * 40 + bk + 8] = *(const short8*)(s0 + 8);
            const short* s1 = &Bl_g[(size_t)(n0 + br) * 256 + k0 + bk];
            *(short8*)&Bl[br * 40 + bk]     = *(const short8*)s1;
            *(short8*)&Bl[br * 40 + bk + 8] = *(const short8*)(s1 + 8);
        }
        __syncthreads();
        int rowA = w * 16 + l15;
        short8 ahi = *(short8*)&Ah[rowA * 40 + q * 8];
        short8 alo = *(short8*)&Al[rowA * 40 + q * 8];
        #pragma unroll
        for (int nt = 0; nt < 8; ++nt) {
            int rowB = nt * 16 + l15;
            short8 bhi = *(short8*)&Bh[rowB * 40 + q * 8];
            short8 blo = *(short8*)&Bl[rowB * 40 + q * 8];
            acc[nt] = __builtin_amdgcn_mfma_f32_16x16x32_bf16(ahi, bhi, acc[nt], 0, 0, 0);
            acc[nt] = __builtin_amdgcn_mfma_f32_16x16x32_bf16(alo, bhi, acc[nt], 0, 0, 0);
            acc[nt] = __builtin_amdgcn_mfma_f32_16x16x32_bf16(ahi, blo, acc[nt], 0, 0, 0);
        }
        __syncthreads();
    }
    #pragma unroll
    for (int nt = 0; nt < 8; ++nt) {
        #pragma unroll
        for (int r = 0; r < 4; ++r) {
            int gm = m0 + w * 16 + q * 4 + r;
            if (gm < M) C[(size_t)gm * 256 + n0 + nt * 16 + l15] = f2h(acc[nt][r]);
        }
    }
}

// -------------------- CSR build --------------------
__global__ void zero_int(int* __restrict__ p, int n) {
    int i = blockIdx.x * 256 + threadIdx.x;
    if (i < n) p[i] = 0;
}

__global__ void hist_kernel(const int* __restrict__ dst, int* __restrict__ deg, int E) {
    int i = blockIdx.x * 256 + threadIdx.x;
    if (i < E) atomicAdd(&deg[dst[i]], 1);
}

__global__ __launch_bounds__(1024) void scan1(const int* __restrict__ deg,
                                              int* __restrict__ lex,
                                              int* __restrict__ bsums, int n) {
    __shared__ int sh[1024];
    int tid = threadIdx.x;
    int i = blockIdx.x * 1024 + tid;
    int v = (i < n) ? deg[i] : 0;
    sh[tid] = v;
    __syncthreads();
    #pragma unroll
    for (int off = 1; off < 1024; off <<= 1) {
        int t2 = (tid >= off) ? sh[tid - off] : 0;
        __syncthreads();
        sh[tid] += t2;
        __syncthreads();
    }
    if (i < n) lex[i] = sh[tid] - v;
    if (tid == 1023) bsums[blockIdx.x] = sh[1023];
}

__global__ __launch_bounds__(1024) void scan2(const int* __restrict__ bsums,
                                              int* __restrict__ boffs,
                                              int* __restrict__ offs, int nb, int n) {
    __shared__ int sh[1024];
    int tid = threadIdx.x;
    int v = (tid < nb) ? bsums[tid] : 0;
    sh[tid] = v;
    __syncthreads();
    #pragma unroll
    for (int off = 1; off < 1024; off <<= 1) {
        int t2 = (tid >= off) ? sh[tid - off] : 0;
        __syncthreads();
        sh[tid] += t2;
        __syncthreads();
    }
    if (tid < nb) boffs[tid] = sh[tid] - v;
    if (tid == nb - 1) offs[n] = sh[tid];
}

__global__ __launch_bounds__(1024) void scan3(int* __restrict__ offs,
                                              int* __restrict__ cur,
                                              const int* __restrict__ boffs, int n) {
    int i = blockIdx.x * 1024 + threadIdx.x;
    if (i < n) {
        int o = offs[i] + boffs[blockIdx.x];
        offs[i] = o;
        cur[i] = o;
    }
}

__global__ void scatter_kernel(const int* __restrict__ src, const int* __restrict__ dst,
                               int* __restrict__ cur, int* __restrict__ sorted, int E) {
    int i = blockIdx.x * 256 + threadIdx.x;
    if (i < E) {
        int p = atomicAdd(&cur[dst[i]], 1);
        sorted[p] = src[i];
    }
}

// -------------------- attention scalars (fp16 hp in) --------------------
template <int NH>
__global__ __launch_bounds__(256) void scompute(const unsigned short* __restrict__ hp,
                                                const float* __restrict__ a_src,
                                                const float* __restrict__ a_dst,
                                                float* __restrict__ s_src,
                                                float* __restrict__ s_dst) {
    __shared__ float w1[4], w2[4];
    int node = blockIdx.x;
    int t = threadIdx.x;
    float v = h2f(hp[(size_t)node * 256 + t]);
    float p1 = v * a_src[t];
    float p2 = v * a_dst[t];
    #pragma unroll
    for (int off = 32; off > 0; off >>= 1) {
        p1 += __shfl_down(p1, off, 64);
        p2 += __shfl_down(p2, off, 64);
    }
    int wave = t >> 6, lane = t & 63;
    if constexpr (NH == 4) {
        if (lane == 0) {
            s_src[node * 4 + wave] = p1;
            s_dst[node * 4 + wave] = p2;
        }
    } else {
        if (lane == 0) { w1[wave] = p1; w2[wave] = p2; }
        __syncthreads();
        if (t == 0) {
            s_src[node] = w1[0] + w1[1] + w1[2] + w1[3];
            s_dst[node] = w2[0] + w2[1] + w2[2] + w2[3];
        }
    }
}

// -------------------- fused stats + aggregation --------------------
template <int NH, bool RELU>
__global__ __launch_bounds__(256) void aggregate4(const unsigned short* __restrict__ hp,
                                                  const float* __restrict__ ssrc,
                                                  const float* __restrict__ sdst,
                                                  const int* __restrict__ offs,
                                                  const int* __restrict__ sorted,
                                                  float* __restrict__ out, int N) {
    const int w = threadIdx.x >> 6, lane = threadIdx.x & 63;
    const int node = blockIdx.x * 4 + w;
    if (node >= N) return;
    constexpr int NF = 256 / NH;
    const int half = lane >> 5;       // which edge of the pair
    const int l32 = lane & 31;
    const int f0 = l32 * 8;           // 8 features per lane
    const int head = f0 / NF;

    const int b = offs[node], e = offs[node + 1];
    const int deg = e - b;

    float sv[NH];
    #pragma unroll
    for (int h = 0; h < NH; ++h) sv[h] = sdst[node * NH + h];

    if (deg == 0) {   // no edges: output zeros
        if (lane < 32) {
            *(float4*)&out[(size_t)node * 256 + f0] = make_float4(0.f, 0.f, 0.f, 0.f);
            *(float4*)&out[(size_t)node * 256 + f0 + 4] = make_float4(0.f, 0.f, 0.f, 0.f);
        }
        return;
    }

    // ---- stats phase ----
    float mx[NH], evc[NH];
    int mys = 0;
    #pragma unroll
    for (int h = 0; h < NH; ++h) { mx[h] = -INFINITY; evc[h] = -INFINITY; }
    for (int c = b + lane; c < e; c += 64) {
        int s = sorted[c];
        mys = s;
        #pragma unroll
        for (int h = 0; h < NH; ++h) {
            float ev = ssrc[s * NH + h] + sv[h];
            ev = ev > 0.f ? ev : 0.2f * ev;
            evc[h] = ev;
            mx[h] = fmaxf(mx[h], ev);
        }
    }
    #pragma unroll
    for (int off = 32; off > 0; off >>= 1)
        #pragma unroll
        for (int h = 0; h < NH; ++h)
            mx[h] = fmaxf(mx[h], __shfl_xor(mx[h], off, 64));

    float pv[NH], lv[NH];
    if (deg <= 64) {
        #pragma unroll
        for (int h = 0; h < NH; ++h) {
            pv[h] = __expf(evc[h] - mx[h]);   // empty lanes: exp(-inf)=0
            lv[h] = pv[h];
        }
    } else {
        #pragma unroll
        for (int h = 0; h < NH; ++h) lv[h] = 0.f;
        for (int c = b + lane; c < e; c += 64) {
            int s = sorted[c];
            #pragma unroll
            for (int h = 0; h < NH; ++h) {
                float ev = ssrc[s * NH + h] + sv[h];
                ev = ev > 0.f ? ev : 0.2f * ev;
                lv[h] += __expf(ev - mx[h]);
            }
        }
    }
    #pragma unroll
    for (int off = 32; off > 0; off >>= 1)
        #pragma unroll
        for (int h = 0; h < NH; ++h)
            lv[h] += __shfl_xor(lv[h], off, 64);
    float linv[NH];
    #pragma unroll
    for (int h = 0; h < NH; ++h) linv[h] = 1.0f / (lv[h] + 1e-16f);

    // ---- main gather loop ----
    float acc[8];
    #pragma unroll
    for (int k = 0; k < 8; ++k) acc[k] = 0.f;

    if (deg <= 64) {
        // Wave-uniform trip count: every lane stays active through each
        // __shfl (bpermute from an exec-masked lane is undefined).
        const int pairs = (deg + 1) >> 1;
        for (int t2 = 0; t2 < pairs; ++t2) {
            int j = 2 * t2 + half;
            bool valid = j < deg;
            int jj = valid ? j : 0;
            int s = __shfl(mys, jj, 64);
            float p;
            if constexpr (NH == 4) {
                float p0 = __shfl(pv[0], jj, 64);
                float p1 = __shfl(pv[1], jj, 64);
                float p2 = __shfl(pv[2], jj, 64);
                float p3 = __shfl(pv[3], jj, 64);
                p = head == 0 ? p0 : head == 1 ? p1 : head == 2 ? p2 : p3;
            } else {
                p = __shfl(pv[0], jj, 64);
            }
            if (!valid) p = 0.f;
            half8 v = *(const half8*)(hp + (size_t)s * 256 + f0);
            #pragma unroll
            for (int k = 0; k < 8; ++k) acc[k] = fmaf(p, (float)v[k], acc[k]);
        }
    } else {
        for (int i = b + half; i < e; i += 2) {
            int s = sorted[i];
            float ev = ssrc[s * NH + head] + sv[head];
            ev = ev > 0.f ? ev : 0.2f * ev;
            float p = __expf(ev - mx[head]);
            half8 v = *(const half8*)(hp + (size_t)s * 256 + f0);
            #pragma unroll
            for (int k = 0; k < 8; ++k) acc[k] = fmaf(p, (float)v[k], acc[k]);
        }
    }

    // combine the two edge-parity halves
    #pragma unroll
    for (int k = 0; k < 8; ++k) acc[k] += __shfl_xor(acc[k], 32, 64);

    if (lane < 32) {
        float li = linv[head];
        float o[8];
        #pragma unroll
        for (int k = 0; k < 8; ++k) {
            o[k] = acc[k] * li;
            if (RELU) o[k] = fmaxf(o[k], 0.f);
        }
        *(float4*)&out[(size_t)node * 256 + f0]     = make_float4(o[0], o[1], o[2], o[3]);
        *(float4*)&out[(size_t)node * 256 + f0 + 4] = make_float4(o[4], o[5], o[6], o[7]);
    }
}

// ---------------------------------------------------------------------------
extern "C" void kernel_launch(void* const* d_in, const int* in_sizes, int n_in,
                              void* d_out, int out_size, void* d_ws, size_t ws_size,
                              hipStream_t stream) {
    const float* x   = (const float*)d_in[0];
    const int*   ei  = (const int*)d_in[1];
    const float* W1  = (const float*)d_in[2];
    const float* a1s = (const float*)d_in[3];
    const float* a1d = (const float*)d_in[4];
    const float* W2  = (const float*)d_in[5];
    const float* a2s = (const float*)d_in[6];
    const float* a2d = (const float*)d_in[7];
    float* out = (float*)d_out;

    const int N = in_sizes[0] / 256;
    const int E = in_sizes[1] / 2;
    const int* src = ei;
    const int* dst = ei + E;

    // workspace carve-up
    unsigned short* hp = (unsigned short*)d_ws;     // N*256 fp16
    float* ssrc  = (float*)(hp + (size_t)N * 256);  // N*4
    float* sdst  = ssrc + (size_t)N * 4;            // N*4
    int*   deg   = (int*)(sdst + (size_t)N * 4);    // N
    int*   cur   = deg + N;                         // N
    int*   offs  = cur + N;                         // N+1
    int*   sorted= offs + N + 1;                    // E
    int*   bsums = sorted + E;                      // 64
    int*   boffs = bsums + 64;                      // 64
    short* w1hi  = (short*)(boffs + 64);            // 65536
    short* w1lo  = w1hi + 65536;
    short* w2hi  = w1lo + 65536;
    short* w2lo  = w2hi + 65536;

    const int nb = (N + 1023) / 1024;

    // ---- weight split ----
    convert_w<<<256, 256, 0, stream>>>(W1, w1hi, w1lo, 65536);
    convert_w<<<256, 256, 0, stream>>>(W2, w2hi, w2lo, 65536);

    // ---- CSR build ----
    zero_int<<<(N + 255) / 256, 256, 0, stream>>>(deg, N);
    hist_kernel<<<(E + 255) / 256, 256, 0, stream>>>(dst, deg, E);
    scan1<<<nb, 1024, 0, stream>>>(deg, offs, bsums, N);
    scan2<<<1, 1024, 0, stream>>>(bsums, boffs, offs, nb, N);
    scan3<<<nb, 1024, 0, stream>>>(offs, cur, boffs, N);
    scatter_kernel<<<(E + 255) / 256, 256, 0, stream>>>(src, dst, cur, sorted, E);

    dim3 gg((N + 63) / 64, 2);
    int aggblocks = (N + 3) / 4;

    // ---- layer 1 ----
    gemm_mfma<<<gg, 256, 0, stream>>>(x, w1hi, w1lo, hp, N);
    scompute<4><<<N, 256, 0, stream>>>(hp, a1s, a1d, ssrc, sdst);
    aggregate4<4, true><<<aggblocks, 256, 0, stream>>>(hp, ssrc, sdst, offs, sorted, out, N);

    // ---- layer 2 (h in d_out fp32; dead before final aggregate overwrites) ----
    gemm_mfma<<<gg, 256, 0, stream>>>(out, w2hi, w2lo, hp, N);
    scompute<1><<<N, 256, 0, stream>>>(hp, a2s, a2d, ssrc, sdst);
    aggregate4<1, false><<<aggblocks, 256, 0, stream>>>(hp, ssrc, sdst, offs, sorted, out, N);
}